// Round 4
// baseline (516.312 us; speedup 1.0000x reference)
//
#include <hip/hip_runtime.h>

#define PITCH 72    // 64+8 bf16 pad for 64-col tiles (qkv kernel)
#define PPITCH 68   // P-scratch pitch: conflict-free for quad-strided rows
#define OSPITCH 68  // O-exchange f32 pitch

typedef __attribute__((ext_vector_type(8))) short bf16x8;
typedef __attribute__((ext_vector_type(4))) float f32x4;
typedef __attribute__((ext_vector_type(8))) unsigned short u16x8;

__device__ __forceinline__ unsigned short f2bf(float f) {
  union { float f; unsigned int u; } v; v.f = f;
  unsigned int u = v.u + 0x7fffu + ((v.u >> 16) & 1u);  // RNE
  return (unsigned short)(u >> 16);
}

__device__ __forceinline__ f32x4 mfma16(bf16x8 a, bf16x8 b, f32x4 c) {
  return __builtin_amdgcn_mfma_f32_16x16x32_bf16(a, b, c, 0, 0, 0);
}

// ---------------------------------------------------------------------------
// Kernel 1: QKV projection, one WG per (m-tile, which) -> grid 768.
// XCD-swizzled so the 3 projections of one m-tile land on the SAME XCD.
// ---------------------------------------------------------------------------
__global__ __launch_bounds__(256) void qkv_kernel(
    const float* __restrict__ x, const float* __restrict__ Wq,
    const float* __restrict__ Wk, const float* __restrict__ Wv,
    unsigned short* __restrict__ q_ws, unsigned short* __restrict__ k_ws,
    unsigned short* __restrict__ vT_ws) {
  __shared__ unsigned short Xs[64 * PITCH];
  __shared__ unsigned short Ws[64 * PITCH];

  const int tid = threadIdx.x;
  const int wave = tid >> 6, lane = tid & 63;
  const int quad = lane >> 4, l16 = lane & 15;
  const int bx = blockIdx.x;
  const int xcd = bx & 7, rr = bx >> 3;
  const int g = rr / 3, which = rr - g * 3;
  const int mt = (g << 3) + xcd;
  const int m0 = mt * 64;
  const float* wp = (which == 0) ? Wq : ((which == 1) ? Wk : Wv);

  f32x4 acc[4];
#pragma unroll
  for (int i = 0; i < 4; ++i) acc[i] = (f32x4)0.0f;

  const int srow = tid >> 4, sc4 = tid & 15;
  for (int k0 = 0; k0 < 1024; k0 += 64) {
#pragma unroll
    for (int i = 0; i < 4; ++i) {
      int row = srow + i * 16;
      float4 f = *(const float4*)(x + (size_t)(m0 + row) * 1024 + k0 + sc4 * 4);
      *(ushort4*)&Xs[row * PITCH + sc4 * 4] =
          make_ushort4(f2bf(f.x), f2bf(f.y), f2bf(f.z), f2bf(f.w));
      float4 gg = *(const float4*)(wp + (size_t)row * 1024 + k0 + sc4 * 4);
      *(ushort4*)&Ws[row * PITCH + sc4 * 4] =
          make_ushort4(f2bf(gg.x), f2bf(gg.y), f2bf(gg.z), f2bf(gg.w));
    }
    __syncthreads();
#pragma unroll
    for (int ks = 0; ks < 64; ks += 32) {
      bf16x8 a = *(const bf16x8*)&Xs[(wave * 16 + l16) * PITCH + ks + quad * 8];
#pragma unroll
      for (int nt = 0; nt < 4; ++nt) {
        bf16x8 b = *(const bf16x8*)&Ws[(nt * 16 + l16) * PITCH + ks + quad * 8];
        acc[nt] = mfma16(a, b, acc[nt]);
      }
    }
    __syncthreads();
  }

  const int mrow = wave * 16 + quad * 4;  // C/D: row=quad*4+r, col=l16
  if (which == 0) {
#pragma unroll
    for (int nt = 0; nt < 4; ++nt)
#pragma unroll
      for (int r = 0; r < 4; ++r)
        q_ws[(size_t)(m0 + mrow + r) * 64 + nt * 16 + l16] = f2bf(acc[nt][r] * 0.125f);
  } else if (which == 1) {
#pragma unroll
    for (int nt = 0; nt < 4; ++nt)
#pragma unroll
      for (int r = 0; r < 4; ++r)
        k_ws[(size_t)(m0 + mrow + r) * 64 + nt * 16 + l16] = f2bf(acc[nt][r]);
  } else {
    // transpose v via LDS, store vT[b][h][t]
#pragma unroll
    for (int nt = 0; nt < 4; ++nt)
#pragma unroll
      for (int r = 0; r < 4; ++r)
        Xs[(nt * 16 + l16) * PITCH + mrow + r] = f2bf(acc[nt + 0][r]);
    __syncthreads();
    const int b = m0 >> 12, t0 = m0 & 4095;
#pragma unroll
    for (int i = 0; i < 2; ++i) {
      int cc = tid + i * 256;
      int h = cc >> 3, c8 = cc & 7;
      u16x8 v = *(const u16x8*)&Xs[h * PITCH + c8 * 8];
      *(u16x8*)(vT_ws + ((size_t)b * 64 + h) * 4096 + t0 + c8 * 8) = v;
    }
  }
}

// ---------------------------------------------------------------------------
// Kernel 2: FUSED attention. Grid 256 = one WG per (b, q-tile of 64 rows).
// 512 threads = 8 waves = 4 q-strips (16 rows) x 2 k-halves (64 of each 128).
// XCD swizzle pins each batch's K/V (1 MB) to one XCD's L2.
// K/V/Q fragments are loaded straight from L2 into registers (no LDS staging,
// no barriers in the K-loops -> compiler software-pipelines with counted
// vmcnt). Pass 1: full-row sumE/sumES/Oacc over all 4096 keys (stats additive,
// no max-subtraction; scores ~N(0,1)). Epilogue: reduce stats, write out +
// entropy. Pass 2: recompute scores, stream attn = exp(s)*invS (nontemporal
// so the 268 MB stream doesn't evict K from L2).
// ---------------------------------------------------------------------------
__global__ __launch_bounds__(512) void fused_kernel(
    const unsigned short* __restrict__ q_ws, const unsigned short* __restrict__ k_ws,
    const unsigned short* __restrict__ vT_ws, float* __restrict__ out,
    float* __restrict__ attn, float* __restrict__ entAcc) {
  __shared__ unsigned short Ps[8][16 * PPITCH];  // per-wave P tile (16q x 64k bf16)
  __shared__ float redE[2][64], redES[2][64];
  __shared__ float invLds[64];

  const int tid = threadIdx.x;
  const int wave = tid >> 6, lane = tid & 63;
  const int quad = lane >> 4, l16 = lane & 15;
  const int qs = wave & 3, kh = wave >> 2;  // q-strip, k-half
  const int bx = blockIdx.x;
  const int xcd = bx & 7, j = bx >> 3;
  const int b = xcd >> 1, qt = (xcd & 1) * 32 + j;  // bijective; 1 batch per XCD
  const int q0 = qt * 64;

  const unsigned short* qb = q_ws + ((size_t)b * 4096 + q0) * 64;
  const unsigned short* kb = k_ws + (size_t)b * 4096 * 64;
  const unsigned short* vtb = vT_ws + (size_t)b * 64 * 4096;

  // Q fragments in registers: lane row = qs*16+l16, cols [ks*32+quad*8, +8)
  bf16x8 aq[2];
#pragma unroll
  for (int ks = 0; ks < 2; ++ks)
    aq[ks] = *(const bf16x8*)(qb + (size_t)(qs * 16 + l16) * 64 + ks * 32 + quad * 8);

  f32x4 Oacc[4];
#pragma unroll
  for (int i = 0; i < 4; ++i) Oacc[i] = (f32x4)0.0f;
  float sumE[4] = {0.f, 0.f, 0.f, 0.f};
  float sumES[4] = {0.f, 0.f, 0.f, 0.f};

  // ---------------- pass 1: stats + O (no barriers) ----------------
  for (int it = 0; it < 32; ++it) {
    const int k0 = it * 128 + kh * 64;
    f32x4 s[4];
#pragma unroll
    for (int i = 0; i < 4; ++i) s[i] = (f32x4)0.0f;
#pragma unroll
    for (int ks = 0; ks < 2; ++ks)
#pragma unroll
      for (int nt = 0; nt < 4; ++nt) {
        bf16x8 bk = *(const bf16x8*)(kb + (size_t)(k0 + nt * 16 + l16) * 64 +
                                     ks * 32 + quad * 8);
        s[nt] = mfma16(aq[ks], bk, s[nt]);
      }
#pragma unroll
    for (int nt = 0; nt < 4; ++nt)
#pragma unroll
      for (int r = 0; r < 4; ++r) {
        float sv = s[nt][r];
        float e = __expf(sv);
        sumE[r] += e;
        sumES[r] += e * sv;
        Ps[wave][(quad * 4 + r) * PPITCH + nt * 16 + l16] = f2bf(e);
      }
#pragma unroll
    for (int kk = 0; kk < 2; ++kk) {
      bf16x8 a = *(const bf16x8*)&Ps[wave][l16 * PPITCH + kk * 32 + quad * 8];
#pragma unroll
      for (int ht = 0; ht < 4; ++ht) {
        bf16x8 bv = *(const bf16x8*)(vtb + (size_t)(ht * 16 + l16) * 4096 + k0 +
                                     kk * 32 + quad * 8);
        Oacc[ht] = mfma16(a, bv, Oacc[ht]);
      }
    }
  }

  // ---------------- epilogue: stats reduce, out, entropy ----------------
#pragma unroll
  for (int off = 1; off < 16; off <<= 1)
#pragma unroll
    for (int r = 0; r < 4; ++r) {
      sumE[r] += __shfl_xor(sumE[r], off, 64);
      sumES[r] += __shfl_xor(sumES[r], off, 64);
    }
  const int mrow = qs * 16 + quad * 4;
  if (l16 == 0)
#pragma unroll
    for (int r = 0; r < 4; ++r) {
      redE[kh][mrow + r] = sumE[r];
      redES[kh][mrow + r] = sumES[r];
    }
  __syncthreads();  // all PV reads of Ps done; redE/redES complete

  float* Osum = (float*)&Ps[0][0];  // reuse 17.4 KB >= 64*OSPITCH*4 B
  if (kh == 1) {
#pragma unroll
    for (int ht = 0; ht < 4; ++ht)
#pragma unroll
      for (int r = 0; r < 4; ++r)
        Osum[(mrow + r) * OSPITCH + ht * 16 + l16] = Oacc[ht][r];
  }
  if (tid < 64) {  // wave 0: per-row softmax denom + entropy
    float S = redE[0][tid] + redE[1][tid];
    float W = redES[0][tid] + redES[1][tid];
    float inv = 1.0f / S;
    invLds[tid] = inv;
    float ent = __logf(S) - W * inv;
#pragma unroll
    for (int off = 1; off < 64; off <<= 1) ent += __shfl_xor(ent, off, 64);
    if (tid == 0) atomicAdd(entAcc, ent);
  }
  __syncthreads();  // Osum + invLds visible

  if (kh == 0) {
#pragma unroll
    for (int ht = 0; ht < 4; ++ht)
#pragma unroll
      for (int r = 0; r < 4; ++r) {
        float o = Oacc[ht][r] + Osum[(mrow + r) * OSPITCH + ht * 16 + l16];
        out[((size_t)b * 4096 + q0 + mrow + r) * 64 + ht * 16 + l16] =
            o * invLds[mrow + r];
      }
  }

  // ---------------- pass 2: attn write (no barriers) ----------------
  float invR[4];
#pragma unroll
  for (int r = 0; r < 4; ++r) invR[r] = invLds[mrow + r];

  float* ab = attn + ((size_t)b * 4096 + q0 + qs * 16) * 4096;
  for (int it = 0; it < 32; ++it) {
    const int k0 = it * 128 + kh * 64;
    f32x4 s[4];
#pragma unroll
    for (int i = 0; i < 4; ++i) s[i] = (f32x4)0.0f;
#pragma unroll
    for (int ks = 0; ks < 2; ++ks)
#pragma unroll
      for (int nt = 0; nt < 4; ++nt) {
        bf16x8 bk = *(const bf16x8*)(kb + (size_t)(k0 + nt * 16 + l16) * 64 +
                                     ks * 32 + quad * 8);
        s[nt] = mfma16(aq[ks], bk, s[nt]);
      }
#pragma unroll
    for (int nt = 0; nt < 4; ++nt)
#pragma unroll
      for (int r = 0; r < 4; ++r)
        __builtin_nontemporal_store(
            __expf(s[nt][r]) * invR[r],
            ab + (size_t)(quad * 4 + r) * 4096 + k0 + nt * 16 + l16);
  }
}

// ---------------------------------------------------------------------------
// Kernel 3: new_energy = 0.9*energy + 0.1*mean_entropy
// ---------------------------------------------------------------------------
__global__ void energy_kernel(const float* __restrict__ energy,
                              const float* __restrict__ entAcc,
                              float* __restrict__ dst) {
  if (threadIdx.x == 0 && blockIdx.x == 0)
    dst[0] = 0.9f * energy[0] + 0.1f * (entAcc[0] * (1.0f / 16384.0f));
}

extern "C" void kernel_launch(void* const* d_in, const int* in_sizes, int n_in,
                              void* d_out, int out_size, void* d_ws, size_t ws_size,
                              hipStream_t stream) {
  (void)in_sizes; (void)n_in; (void)out_size; (void)ws_size;
  const float* x = (const float*)d_in[0];
  const float* Wq = (const float*)d_in[1];
  const float* Wk = (const float*)d_in[2];
  const float* Wv = (const float*)d_in[3];
  const float* energy = (const float*)d_in[4];

  float* out = (float*)d_out;                          // [4,4096,64]
  float* attn = out + (size_t)4 * 4096 * 64;           // [4,4096,4096]
  float* dst_energy = attn + (size_t)4 * 4096 * 4096;  // scalar

  char* ws = (char*)d_ws;
  float* entAcc = (float*)ws;                          // 4 B (pad 256)
  unsigned short* q_ws = (unsigned short*)(ws + 256);  // 2 MB
  unsigned short* k_ws = q_ws + (size_t)16384 * 64;    // 2 MB
  unsigned short* vT_ws = k_ws + (size_t)16384 * 64;   // 2 MB

  hipMemsetAsync(entAcc, 0, sizeof(float), stream);
  qkv_kernel<<<768, 256, 0, stream>>>(x, Wq, Wk, Wv, q_ws, k_ws, vT_ws);
  fused_kernel<<<256, 512, 0, stream>>>(q_ws, k_ws, vT_ws, out, attn, entAcc);
  energy_kernel<<<1, 64, 0, stream>>>(energy, entAcc, dst_energy);
}